// Round 1
// baseline (374.999 us; speedup 1.0000x reference)
//
#include <hip/hip_runtime.h>
#include <math.h>

#define NBATCH 2048
#define LSEQ   2048
#define DK     64
#define DV     64

// One block per batch row b. 256 threads = 4 waves.
// Thread layout for K/V streaming: rloc = tid>>4 (16 rows per tile),
// e4 = tid&15 (float4 column within the 64-float row).
__global__ __launch_bounds__(256) void mvsdpa_kernel(
    const float* __restrict__ q,    // [NB, DK]
    const float* __restrict__ k,    // [NB, L, DK]
    const float* __restrict__ v,    // [NB, L, DV]
    float* __restrict__ out,        // [NB, DV]
    float* __restrict__ attn)       // [NB, L]
{
    const int b    = blockIdx.x;
    const int tid  = threadIdx.x;
    const int e4   = tid & 15;   // float4 index within row
    const int rloc = tid >> 4;   // 0..15

    __shared__ float s_lds[LSEQ];        // scores, then normalized p (8 KB)
    __shared__ float red[16];            // cross-wave reduction scratch
    __shared__ float p_part[16][DV];     // pass-2 partials (4 KB)

    // q fragment for this thread's column group
    const float4 q4 = reinterpret_cast<const float4*>(q + (size_t)b * DK)[e4];

    // ---------------- Pass 1: scores s[l] = (q . k[b,l]) / 8 ----------------
    const float4* kb = reinterpret_cast<const float4*>(k + (size_t)b * LSEQ * DK);
    for (int l0 = 0; l0 < LSEQ; l0 += 16) {
        const int l = l0 + rloc;
        const float4 k4 = kb[(size_t)l * (DK / 4) + e4];
        float partial = q4.x * k4.x + q4.y * k4.y + q4.z * k4.z + q4.w * k4.w;
        // reduce across the 16-lane column group (stays within the group)
        partial += __shfl_xor(partial, 1);
        partial += __shfl_xor(partial, 2);
        partial += __shfl_xor(partial, 4);
        partial += __shfl_xor(partial, 8);
        if (e4 == 0) s_lds[l] = partial * 0.125f;
    }
    __syncthreads();

    // ---------------- Softmax over LSEQ in LDS ----------------
    const int wave = tid >> 6;
    const int lane = tid & 63;

    // block max
    float m = -INFINITY;
    #pragma unroll
    for (int j = 0; j < LSEQ / 256; ++j) m = fmaxf(m, s_lds[tid + j * 256]);
    #pragma unroll
    for (int off = 1; off < 64; off <<= 1) m = fmaxf(m, __shfl_xor(m, off));
    if (lane == 0) red[wave] = m;
    __syncthreads();
    m = fmaxf(fmaxf(red[0], red[1]), fmaxf(red[2], red[3]));

    // exp + sum (each thread owns indices tid + j*256 exclusively)
    float pv[LSEQ / 256];
    float ssum = 0.f;
    #pragma unroll
    for (int j = 0; j < LSEQ / 256; ++j) {
        const float p = __expf(s_lds[tid + j * 256] - m);
        pv[j] = p;
        ssum += p;
    }
    #pragma unroll
    for (int off = 1; off < 64; off <<= 1) ssum += __shfl_xor(ssum, off);
    if (lane == 0) red[8 + wave] = ssum;   // disjoint slots: no race with red[0..3] reads
    __syncthreads();
    const float inv = 1.0f / (red[8] + red[9] + red[10] + red[11]);

    // normalize: store p to LDS and write attn[b] to global (coalesced)
    float* attn_b = attn + (size_t)b * LSEQ;
    #pragma unroll
    for (int j = 0; j < LSEQ / 256; ++j) {
        const int i = tid + j * 256;
        const float p = pv[j] * inv;
        s_lds[i] = p;
        attn_b[i] = p;
    }
    __syncthreads();

    // ---------------- Pass 2: out[b,e] = sum_l p[l] * v[b,l,e] ----------------
    const float4* vb = reinterpret_cast<const float4*>(v + (size_t)b * LSEQ * DV);
    float4 acc = make_float4(0.f, 0.f, 0.f, 0.f);
    for (int l0 = 0; l0 < LSEQ; l0 += 16) {
        const int l = l0 + rloc;
        const float p = s_lds[l];
        const float4 v4 = vb[(size_t)l * (DV / 4) + e4];
        acc.x += p * v4.x;
        acc.y += p * v4.y;
        acc.z += p * v4.z;
        acc.w += p * v4.w;
    }
    reinterpret_cast<float4*>(p_part[rloc])[e4] = acc;
    __syncthreads();

    if (tid < DV) {
        float s = 0.f;
        #pragma unroll
        for (int r = 0; r < 16; ++r) s += p_part[r][tid];
        out[(size_t)b * DV + tid] = s;
    }
}

extern "C" void kernel_launch(void* const* d_in, const int* in_sizes, int n_in,
                              void* d_out, int out_size, void* d_ws, size_t ws_size,
                              hipStream_t stream) {
    const float* q = (const float*)d_in[0];
    const float* k = (const float*)d_in[1];
    const float* v = (const float*)d_in[2];
    float* out  = (float*)d_out;                       // [NB, DV]
    float* attn = (float*)d_out + (size_t)NBATCH * DV; // [NB, L]

    mvsdpa_kernel<<<NBATCH, 256, 0, stream>>>(q, k, v, out, attn);
}